// Round 6
// baseline (1124.588 us; speedup 1.0000x reference)
//
#include <hip/hip_runtime.h>

namespace {

typedef __attribute__((ext_vector_type(8))) short short8;   // 8 bf16 (4 VGPRs)
typedef __attribute__((ext_vector_type(4))) float f32x4;

constexpr int T_LEN = 512;
constexpr int ROWS  = 8;     // batch rows per block (8 -> 512 blocks -> 2 blocks/CU)
constexpr int HSTR  = 40;    // h-plane row stride (shorts): 32 used + 8 pad, 80B (16B-mult)

__device__ __forceinline__ float fsig(float x) {
    return __builtin_amdgcn_rcpf(1.0f + __expf(-x));
}
__device__ __forceinline__ float ftanh(float x) {
    return 2.0f * __builtin_amdgcn_rcpf(1.0f + __expf(-2.0f * x)) - 1.0f;
}
__device__ __forceinline__ f32x4 mfma16(short8 a, short8 b, f32x4 c) {
    return __builtin_amdgcn_mfma_f32_16x16x32_bf16(a, b, c, 0, 0, 0);
}
// pack bf16-truncations of (a,b) into one dword, b in LOW short
__device__ __forceinline__ unsigned permhi(float a, float b) {
    return __builtin_amdgcn_perm(__float_as_uint(a), __float_as_uint(b), 0x07060302u);
}
__device__ __forceinline__ float lo_resid(float v) {
    return v - __uint_as_float(__float_as_uint(v) & 0xffff0000u);
}
__device__ __forceinline__ short hi16(float v) {
    return (short)(__float_as_uint(v) >> 16);
}

// Relaxed per-step sync: drain LDS ops (handoff visibility) but let global x
// prefetch loads stay in flight across the barrier (avoids __syncthreads'
// implicit vmcnt(0) drain, ~300-500 cyc/step when prefetching from HBM).
__device__ __forceinline__ void step_sync() {
    asm volatile("s_waitcnt lgkmcnt(0)" ::: "memory");
    __builtin_amdgcn_s_barrier();
    __builtin_amdgcn_sched_barrier(0);
}

__device__ __forceinline__ void load_x(int q, int n, const float4* xg4, int t,
                                       float4& ra, float4& rb) {
    if (q < 2 && n < ROWS) {
        const float4* s = xg4 + (size_t)n * (T_LEN * 4) + (size_t)t * 4 + 2 * q;
        ra = s[0]; rb = s[1];
    }
}

__device__ __forceinline__ void pack_x(int q, const float4& va, const float4& vb,
                                       short8& xh8, short8& xl8) {
    if (q < 2) {
        union { short8 s; uint4 u; } h, l;
        h.u.x = permhi(va.y, va.x); h.u.y = permhi(va.w, va.z);
        h.u.z = permhi(vb.y, vb.x); h.u.w = permhi(vb.w, vb.z);
        l.u.x = permhi(lo_resid(va.y), lo_resid(va.x));
        l.u.y = permhi(lo_resid(va.w), lo_resid(va.z));
        l.u.z = permhi(lo_resid(vb.y), lo_resid(vb.x));
        l.u.w = permhi(lo_resid(vb.w), lo_resid(vb.z));
        xh8 = h.s; xl8 = l.s;
    }
}

// EW gated to q<2: with ROWS=8 only D rows 0..7 (q*4+r) are live batch rows.
__device__ __forceinline__ void ew_write(const f32x4 (&gg)[4], float (&cst)[4],
                                         short* dhi, short* dlo, int q, int n, int p) {
    if (q < 2) {
        #pragma unroll
        for (int r = 0; r < 4; ++r) {
            const float ig = fsig(gg[0][r]);
            const float fg = fsig(gg[1][r]);
            const float gv = ftanh(gg[2][r]);
            const float og = fsig(gg[3][r]);
            const float cc = fg * cst[r] + ig * gv;
            cst[r] = cc;
            const float hv = og * ftanh(cc);
            const int ro = (q * 4 + r) * HSTR + 2 * n + p;
            dhi[ro] = hi16(hv);
            dlo[ro] = hi16(lo_resid(hv));
        }
    }
}

// block = 256 threads = 4 waves over the SAME 8 batch rows (512 blocks = 2/CU).
// waves 0,1 = layer-1 (parity p = wid&1), waves 2,3 = layer-2 (p = wid&1) + MLP head.
// Two independent blocks per CU -> 2 waves/SIMD whose stalls interleave.
// L1 x-terms (Wih0*x_t + bias) precomputed 2 steps ahead into register pre-banks
// via 12 filler MFMAs/step, x loaded global->regs (prefetch stays in flight across
// the relaxed barrier). L1 critical path = 2 ds_reads + 12 MFMAs + EW. L2 = two
// independent 3-chains + f32x4 add. Loop unrolled x4: ring slots/pre-banks static.
// Ring-slot parities are (k+1)&1 / k&1 (NOT k^1 -- R3 bug). One barrier per step.
__global__ __launch_bounds__(256)
void lstm2_pre8_kernel(const float* __restrict__ x,
                       const float* __restrict__ Wih0, const float* __restrict__ Whh0,
                       const float* __restrict__ bih0, const float* __restrict__ bhh0,
                       const float* __restrict__ Wih1, const float* __restrict__ Whh1,
                       const float* __restrict__ bih1, const float* __restrict__ bhh1,
                       const float* __restrict__ W1, const float* __restrict__ b1,
                       const float* __restrict__ W2, const float* __restrict__ b2,
                       float* __restrict__ out)
{
    __shared__ __align__(16) short sh1hi[2][16 * HSTR], sh1lo[2][16 * HSTR]; // h1 ring
    __shared__ __align__(16) short sh2hi[2][16 * HSTR], sh2lo[2][16 * HSTR]; // h2 ring

    const int tid  = threadIdx.x;
    const int wid  = tid >> 6;           // 0,1 = L1; 2,3 = L2
    const int lane = tid & 63;
    const int q    = lane >> 4;          // quad
    const int n    = lane & 15;          // MFMA col (B: unit col) / A batch row
    const bool isL1 = (wid < 2);
    const int p    = wid & 1;            // unit parity owned by this wave

    // ---- zero h planes (rows 8..15 stay zero forever: read-as-zero A rows) ----
    for (int i = tid; i < 16 * HSTR; i += 256) {
        sh1hi[0][i] = 0; sh1hi[1][i] = 0; sh1lo[0][i] = 0; sh1lo[1][i] = 0;
        sh2hi[0][i] = 0; sh2hi[1][i] = 0; sh2lo[0][i] = 0; sh2lo[1][i] = 0;
    }

    // ---- per-wave persistent weight B-fragments + bias C-operands ----
    // chunk for gate g covers unit cols 2n+p (ALL n=0..15 needed: units are N dim).
    // L1: bh/bl[g][0] = Whh0 (K=0..31), bh/bl[g][1] = [Wih0 (k<16) | 0]  (pre-B-frag)
    // L2: bh/bl[g][0] = Wih1 (h1-terms), bh/bl[g][1] = Whh1 (h2-terms)
    short8 bh[4][2], bl[4][2];
    f32x4  bsp[4];
    #pragma unroll
    for (int gate = 0; gate < 4; ++gate) {
        const int row = gate * 32 + 2 * n + p;
        #pragma unroll
        for (int f = 0; f < 2; ++f) {
            #pragma unroll
            for (int e = 0; e < 8; ++e) {
                const int kk = f * 32 + q * 8 + e;
                float v;
                if (isL1) v = (kk < 32) ? Whh0[row * 32 + kk]
                            : (kk < 48) ? Wih0[row * 16 + (kk - 32)] : 0.0f;
                else      v = (kk < 32) ? Wih1[row * 32 + kk]
                                        : Whh1[row * 32 + (kk - 32)];
                const unsigned b = __float_as_uint(v);
                bh[gate][f][e] = (short)(b >> 16);
                const float hif = __uint_as_float(b & 0xffff0000u);
                bl[gate][f][e] = (short)(__float_as_uint(v - hif) >> 16);
            }
        }
        const float bv = isL1 ? (bih0[row] + bhh0[row]) : (bih1[row] + bhh1[row]);
        bsp[gate] = (f32x4){bv, bv, bv, bv};
    }

    float cst[4];                        // c-state (c1 for L1 waves, c2 for L2 waves)
    #pragma unroll
    for (int r = 0; r < 4; ++r) cst[r] = 0.f;

    const float4* xg4 = (const float4*)x + (size_t)blockIdx.x * ROWS * (T_LEN * 4);

    // ---- L1 prologue: build pre(0), pre(1); prefetch x(2), x(3) ----
    float4 r0a{}, r0b{}, r1a{}, r1b{};
    short8 xh0 = (short8)(short)0, xl0 = (short8)(short)0;
    short8 xh1 = (short8)(short)0, xl1 = (short8)(short)0;
    f32x4 pA0[4], pA1[4], pB0[4], pB1[4];
    if (isL1) {
        load_x(q, n, xg4, 0, r0a, r0b);
        load_x(q, n, xg4, 1, r1a, r1b);
        pack_x(q, r0a, r0b, xh0, xl0);
        pack_x(q, r1a, r1b, xh1, xl1);
        #pragma unroll
        for (int g2 = 0; g2 < 4; ++g2) {
            f32x4 c = mfma16(xh0, bh[g2][1], bsp[g2]);
            c = mfma16(xl0, bh[g2][1], c);
            c = mfma16(xh0, bl[g2][1], c);
            pA0[g2] = c;
            f32x4 d = mfma16(xh1, bh[g2][1], bsp[g2]);
            d = mfma16(xl1, bh[g2][1], d);
            d = mfma16(xh1, bl[g2][1], d);
            pA1[g2] = d;
        }
        load_x(q, n, xg4, 2, r0a, r0b);
        load_x(q, n, xg4, 3, r1a, r1b);
    }

    step_sync();                         // h-plane zeros visible

    #pragma unroll 1
    for (int i = 0; i < T_LEN; i += 4) {
        #pragma unroll
        for (int k = 0; k < 4; ++k) {
            const int t = i + k;
            if (isL1) {
                // pack x(t+2) (loaded 2 steps ago) for the pre-build below
                const bool more = (i + k + 2 < T_LEN);
                if (more) {
                    if ((k & 1) == 0) pack_x(q, r0a, r0b, xh0, xl0);
                    else              pack_x(q, r1a, r1b, xh1, xl1);
                }
                // recurrent part: h-terms only, C-init = pre[t]
                const int RS = (k + 1) & 1, WS = k & 1;   // ring slots (static)
                const short8 a0h = *(const short8*)&sh1hi[RS][n * HSTR + q * 8];
                const short8 a0l = *(const short8*)&sh1lo[RS][n * HSTR + q * 8];
                f32x4 gg[4];
                #pragma unroll
                for (int g2 = 0; g2 < 4; ++g2) {
                    f32x4 c = (k == 0) ? pA0[g2] : (k == 1) ? pA1[g2]
                            : (k == 2) ? pB0[g2] : pB1[g2];
                    c = mfma16(a0h, bh[g2][0], c);
                    c = mfma16(a0l, bh[g2][0], c);
                    c = mfma16(a0h, bl[g2][0], c);
                    gg[g2] = c;
                }
                ew_write(gg, cst, &sh1hi[WS][0], &sh1lo[WS][0], q, n, p);
                // filler: build pre(t+2) into the opposite bank; prefetch x(t+4)
                if (more) {
                    const short8 xh = (k & 1) ? xh1 : xh0;
                    const short8 xl = (k & 1) ? xl1 : xl0;
                    #pragma unroll
                    for (int g2 = 0; g2 < 4; ++g2) {
                        f32x4 c = mfma16(xh, bh[g2][1], bsp[g2]);
                        c = mfma16(xl, bh[g2][1], c);
                        c = mfma16(xh, bl[g2][1], c);
                        if (k == 0)      pB0[g2] = c;
                        else if (k == 1) pB1[g2] = c;
                        else if (k == 2) pA0[g2] = c;
                        else             pA1[g2] = c;
                    }
                    const int tn = (t + 4 < T_LEN) ? (t + 4) : (T_LEN - 1);
                    if ((k & 1) == 0) load_x(q, n, xg4, tn, r0a, r0b);
                    else              load_x(q, n, xg4, tn, r1a, r1b);
                }
            } else {
                if (i + k >= 1) {                         // t2 = t-1
                    const int S1 = (k + 1) & 1;           // slot holding h1_{t-1}
                    const int PS2 = k & 1;                // slot holding h2_{t-2}
                    const int W2 = (k + 1) & 1;           // slot receiving h2_{t-1}
                    const short8 a0h = *(const short8*)&sh1hi[S1][n * HSTR + q * 8];
                    const short8 a0l = *(const short8*)&sh1lo[S1][n * HSTR + q * 8];
                    const short8 a1h = *(const short8*)&sh2hi[PS2][n * HSTR + q * 8];
                    const short8 a1l = *(const short8*)&sh2lo[PS2][n * HSTR + q * 8];
                    f32x4 gg[4];
                    #pragma unroll
                    for (int g2 = 0; g2 < 4; ++g2) {
                        f32x4 c1 = mfma16(a0h, bh[g2][0], bsp[g2]);
                        c1 = mfma16(a0l, bh[g2][0], c1);
                        c1 = mfma16(a0h, bl[g2][0], c1);
                        f32x4 c2 = mfma16(a1h, bh[g2][1], (f32x4){0.f, 0.f, 0.f, 0.f});
                        c2 = mfma16(a1l, bh[g2][1], c2);
                        c2 = mfma16(a1h, bl[g2][1], c2);
                        gg[g2] = c1 + c2;
                    }
                    ew_write(gg, cst, &sh2hi[W2][0], &sh2lo[W2][0], q, n, p);
                }
            }
            step_sync();
        }
    }

    // ---- epilogue: L2 for t2 = 511 (slots: S1=1, PS2=0, W2=1) ----
    if (!isL1) {
        const short8 a0h = *(const short8*)&sh1hi[1][n * HSTR + q * 8];
        const short8 a0l = *(const short8*)&sh1lo[1][n * HSTR + q * 8];
        const short8 a1h = *(const short8*)&sh2hi[0][n * HSTR + q * 8];
        const short8 a1l = *(const short8*)&sh2lo[0][n * HSTR + q * 8];
        f32x4 gg[4];
        #pragma unroll
        for (int g2 = 0; g2 < 4; ++g2) {
            f32x4 c1 = mfma16(a0h, bh[g2][0], bsp[g2]);
            c1 = mfma16(a0l, bh[g2][0], c1);
            c1 = mfma16(a0h, bl[g2][0], c1);
            f32x4 c2 = mfma16(a1h, bh[g2][1], (f32x4){0.f, 0.f, 0.f, 0.f});
            c2 = mfma16(a1l, bh[g2][1], c2);
            c2 = mfma16(a1h, bl[g2][1], c2);
            gg[g2] = c1 + c2;
        }
        ew_write(gg, cst, &sh2hi[1][0], &sh2lo[1][0], q, n, p);
    }
    step_sync();

    // ---- MLP head on h2_{T-1} (slot 1), rows 0..7 ----
    if (wid == 2 && lane < ROWS) {
        float h2v[32];
        #pragma unroll
        for (int kk = 0; kk < 32; ++kk) {
            h2v[kk] = __uint_as_float(((unsigned)(unsigned short)sh2hi[1][lane * HSTR + kk]) << 16)
                    + __uint_as_float(((unsigned)(unsigned short)sh2lo[1][lane * HSTR + kk]) << 16);
        }
        float pacc = b2[0];
        #pragma unroll 1
        for (int jj = 0; jj < 16; ++jj) {
            float acc = b1[jj];
            #pragma unroll
            for (int kk = 0; kk < 32; ++kk) acc += W1[jj * 32 + kk] * h2v[kk];
            pacc += W2[jj] * fmaxf(acc, 0.f);
        }
        out[blockIdx.x * ROWS + lane] = pacc;
    }
}

} // namespace

extern "C" void kernel_launch(void* const* d_in, const int* in_sizes, int n_in,
                              void* d_out, int out_size, void* d_ws, size_t ws_size,
                              hipStream_t stream) {
    const float* x    = (const float*)d_in[0];
    const float* Wih0 = (const float*)d_in[1];
    const float* Whh0 = (const float*)d_in[2];
    const float* bih0 = (const float*)d_in[3];
    const float* bhh0 = (const float*)d_in[4];
    const float* Wih1 = (const float*)d_in[5];
    const float* Whh1 = (const float*)d_in[6];
    const float* bih1 = (const float*)d_in[7];
    const float* bhh1 = (const float*)d_in[8];
    const float* W1   = (const float*)d_in[9];
    const float* b1   = (const float*)d_in[10];
    const float* W2   = (const float*)d_in[11];
    const float* b2   = (const float*)d_in[12];

    const int batch  = out_size;            // 4096
    const int blocks = batch / ROWS;        // 512 blocks x 4 waves -> 2 blocks/CU

    hipLaunchKernelGGL(lstm2_pre8_kernel, dim3(blocks), dim3(256), 0, stream,
                       x, Wih0, Whh0, bih0, bhh0, Wih1, Whh1, bih1, bhh1,
                       W1, b1, W2, b2, (float*)d_out);
}

// Round 7
// 766.781 us; speedup vs baseline: 1.4666x; 1.4666x over previous
//
#include <hip/hip_runtime.h>

namespace {

typedef __attribute__((ext_vector_type(8))) short short8;   // 8 bf16 (4 VGPRs)
typedef __attribute__((ext_vector_type(4))) float f32x4;

constexpr int T_LEN = 512;
constexpr int TC    = 16;    // timesteps per x-staging chunk
constexpr int HSTR  = 40;    // h-plane row stride (shorts): 32 used + 8 pad, 80B (16B-mult)
constexpr int XSTR  = 264;   // x-plane row stride (shorts): 256 used + 8 pad, 528B (16B-mult)

__device__ __forceinline__ float fsig(float x) {
    return __builtin_amdgcn_rcpf(1.0f + __expf(-x));
}
__device__ __forceinline__ float ftanh(float x) {
    return 2.0f * __builtin_amdgcn_rcpf(1.0f + __expf(-2.0f * x)) - 1.0f;
}
__device__ __forceinline__ f32x4 mfma16(short8 a, short8 b, f32x4 c) {
    return __builtin_amdgcn_mfma_f32_16x16x32_bf16(a, b, c, 0, 0, 0);
}
// pack bf16-truncations of (a,b) into one dword, b in LOW short
__device__ __forceinline__ unsigned permhi(float a, float b) {
    return __builtin_amdgcn_perm(__float_as_uint(a), __float_as_uint(b), 0x07060302u);
}
__device__ __forceinline__ float lo_resid(float v) {
    return v - __uint_as_float(__float_as_uint(v) & 0xffff0000u);
}
__device__ __forceinline__ short hi16(float v) {
    return (short)(__float_as_uint(v) >> 16);
}

// block = 512 threads = 8 waves = TWO independent 8-row LSTM groups (g = tid>>8).
// Within a group (exact R1 structure): waves {0,1} = layer-1 (parity p), waves
// {2,3} = layer-2 (parity p) + MLP head. 256 blocks x 8 waves -> 2 waves/SIMD
// GUARANTEED co-resident (single workgroup), so the two groups' latency stalls
// interleave and MFMA/VALU issue from different waves co-schedule (m114).
// R5 post-mortem: 2 separate blocks/CU failed to co-reside because the precompute
// variant's VGPR+AGPR total exceeded 256/wave (rocprof VGPR_Count excludes AGPRs)
// -> 1 wave/SIMD. This kernel returns to the lean R1 register footprint (~70).
// A-rows 8..15 read zeros (dead D-rows), EW gated to q<2 -> live-row math is
// bit-identical to R1 (D row r depends only on A row r). One barrier per step.
__global__ __launch_bounds__(512, 2)
void lstm2_dual8_kernel(const float* __restrict__ x,
                        const float* __restrict__ Wih0, const float* __restrict__ Whh0,
                        const float* __restrict__ bih0, const float* __restrict__ bhh0,
                        const float* __restrict__ Wih1, const float* __restrict__ Whh1,
                        const float* __restrict__ bih1, const float* __restrict__ bhh1,
                        const float* __restrict__ W1, const float* __restrict__ b1,
                        const float* __restrict__ W2, const float* __restrict__ b2,
                        float* __restrict__ out)
{
    __shared__ __align__(16) short sh1hi[2][2][16 * HSTR], sh1lo[2][2][16 * HSTR]; // [grp][slot]
    __shared__ __align__(16) short sh2hi[2][2][16 * HSTR], sh2lo[2][2][16 * HSTR];
    __shared__ __align__(16) short sxhi[16 * XSTR],        sxlo[16 * XSTR];        // x chunk (16 rows)
    __shared__ __align__(16) unsigned szero[8];                                    // zero pad

    const int tid  = threadIdx.x;
    const int g    = tid >> 8;           // batch sub-group (8 rows each)
    const int wid4 = (tid >> 6) & 3;     // role within group: 0,1 = L1; 2,3 = L2
    const int lane = tid & 63;
    const int q    = lane >> 4;          // quad (K-subrange of A-frag / D-row block)
    const int n    = lane & 15;          // MFMA col (B: unit col) / A batch row
    const bool isL1 = (wid4 < 2);
    const int p    = wid4 & 1;           // unit parity owned by this wave

    // ---- zero h planes (rows 8..15 stay zero forever: read-as-zero A rows) ----
    for (int i = tid; i < 16 * HSTR; i += 512) {
        sh1hi[0][0][i] = 0; sh1hi[0][1][i] = 0; sh1hi[1][0][i] = 0; sh1hi[1][1][i] = 0;
        sh1lo[0][0][i] = 0; sh1lo[0][1][i] = 0; sh1lo[1][0][i] = 0; sh1lo[1][1][i] = 0;
        sh2hi[0][0][i] = 0; sh2hi[0][1][i] = 0; sh2hi[1][0][i] = 0; sh2hi[1][1][i] = 0;
        sh2lo[0][0][i] = 0; sh2lo[0][1][i] = 0; sh2lo[1][0][i] = 0; sh2lo[1][1][i] = 0;
    }
    if (tid < 8) szero[tid] = 0u;

    // ---- per-wave persistent weight B-fragments + bias C-operands ----
    // chunk for gate g2 covers unit cols 2n+p.
    // L1 K-map: k 0..31 = h1_{t-1}, 32..47 = x_t, 48..63 = 0
    // L2 K-map: k 0..31 = h1_t,     32..63 = h2_{t-1}
    short8 bh[4][2], bl[4][2];
    f32x4  bsp[4];
    #pragma unroll
    for (int gate = 0; gate < 4; ++gate) {
        const int row = gate * 32 + 2 * n + p;
        #pragma unroll
        for (int f = 0; f < 2; ++f) {
            #pragma unroll
            for (int e = 0; e < 8; ++e) {
                const int kk = f * 32 + q * 8 + e;
                float v;
                if (isL1) v = (kk < 32) ? Whh0[row * 32 + kk]
                            : (kk < 48) ? Wih0[row * 16 + (kk - 32)] : 0.0f;
                else      v = (kk < 32) ? Wih1[row * 32 + kk]
                                        : Whh1[row * 32 + (kk - 32)];
                const unsigned b = __float_as_uint(v);
                bh[gate][f][e] = (short)(b >> 16);
                const float hif = __uint_as_float(b & 0xffff0000u);
                bl[gate][f][e] = (short)(__float_as_uint(v - hif) >> 16);
            }
        }
        const float bv = isL1 ? (bih0[row] + bhh0[row]) : (bih1[row] + bhh1[row]);
        bsp[gate] = (f32x4){bv, bv, bv, bv};
    }

    float cst[4];                        // c-state (only q<2 lanes' values are live)
    #pragma unroll
    for (int r = 0; r < 4; ++r) cst[r] = 0.f;

    const float4* xg = (const float4*)x + (size_t)blockIdx.x * 16 * (T_LEN * 4);

    #pragma unroll 1
    for (int i = 0; i <= T_LEN; ++i) {
        if (i < T_LEN && (i & (TC - 1)) == 0) {
            __syncthreads();            // prior chunk's reads (iter i-1) are done
            // stage x[t0 = i .. i+15] for all 16 block rows (both groups help)
            const int b = tid & 15, w = tid >> 4;     // batch row, 32 threads/row
            const float4* src = xg + (size_t)b * (T_LEN * 4) + (size_t)i * 4;
            short* dh = &sxhi[b * XSTR];
            short* dl = &sxlo[b * XSTR];
            #pragma unroll
            for (int ii = 0; ii < 2; ++ii) {
                const int el = w + ii * 32;           // float4 index within chunk row
                const float4 v = src[el];
                uint2 hp, lp;
                hp.x = permhi(v.y, v.x);
                hp.y = permhi(v.w, v.z);
                lp.x = permhi(lo_resid(v.y), lo_resid(v.x));
                lp.y = permhi(lo_resid(v.w), lo_resid(v.z));
                *(uint2*)&dh[el * 4] = hp;
                *(uint2*)&dl[el * 4] = lp;
            }
        }
        __syncthreads();

        const bool active = isL1 ? (i < T_LEN) : (i >= 1);
        if (active) {
            const int t = isL1 ? i : (i - 1);
            const short *pa0h, *pa0l, *pa1h, *pa1l;
            short *dhi, *dlo;
            if (isL1) {
                const int ps = (t + 1) & 1;           // slot holding h1_{t-1}
                const int cs = t & 1;                 // slot receiving h1_t
                const int tt = t & (TC - 1);
                pa0h = &sh1hi[g][ps][n * HSTR + q * 8];
                pa0l = &sh1lo[g][ps][n * HSTR + q * 8];
                // q>=2: K 48..63 zero pad; n>=8: nonexistent batch row -> zeros
                const bool xv = (q < 2) && (n < 8);
                pa1h = xv ? &sxhi[(g * 8 + n) * XSTR + tt * 16 + q * 8] : (const short*)szero;
                pa1l = xv ? &sxlo[(g * 8 + n) * XSTR + tt * 16 + q * 8] : (const short*)szero;
                dhi = sh1hi[g][cs]; dlo = sh1lo[g][cs];
            } else {
                const int s1  = t & 1;                // slot holding h1_t
                const int ps2 = (t + 1) & 1;          // slot holding h2_{t-1}
                pa0h = &sh1hi[g][s1][n * HSTR + q * 8];
                pa0l = &sh1lo[g][s1][n * HSTR + q * 8];
                pa1h = &sh2hi[g][ps2][n * HSTR + q * 8];
                pa1l = &sh2lo[g][ps2][n * HSTR + q * 8];
                dhi = sh2hi[g][t & 1]; dlo = sh2lo[g][t & 1];
            }
            const short8 a0h = *(const short8*)pa0h;
            const short8 a0l = *(const short8*)pa0l;
            const short8 a1h = *(const short8*)pa1h;
            const short8 a1l = *(const short8*)pa1l;

            f32x4 gg[4];
            #pragma unroll
            for (int gate = 0; gate < 4; ++gate) {
                f32x4 acc = mfma16(a0h, bh[gate][0], bsp[gate]);
                acc = mfma16(a1h, bh[gate][1], acc);
                acc = mfma16(a0l, bh[gate][0], acc);
                acc = mfma16(a1l, bh[gate][1], acc);
                acc = mfma16(a0h, bl[gate][0], acc);
                acc = mfma16(a1h, bl[gate][1], acc);
                gg[gate] = acc;
            }
            if (q < 2) {                 // live D-rows 0..7 only
                #pragma unroll
                for (int r = 0; r < 4; ++r) {
                    const float ig = fsig(gg[0][r]);
                    const float fg = fsig(gg[1][r]);
                    const float gv = ftanh(gg[2][r]);
                    const float og = fsig(gg[3][r]);
                    const float cc = fg * cst[r] + ig * gv;
                    cst[r] = cc;
                    const float hv = og * ftanh(cc);
                    const int ro = (q * 4 + r) * HSTR + 2 * n + p;
                    dhi[ro] = hi16(hv);
                    dlo[ro] = hi16(lo_resid(hv));
                }
            }
        }
    }

    // ---- MLP head on h2_{T-1} (slot (T_LEN-1)&1 = 1), per group ----
    __syncthreads();
    if (wid4 == 2 && lane < 8) {
        float h2v[32];
        #pragma unroll
        for (int kk = 0; kk < 32; ++kk) {
            h2v[kk] = __uint_as_float(((unsigned)(unsigned short)sh2hi[g][1][lane * HSTR + kk]) << 16)
                    + __uint_as_float(((unsigned)(unsigned short)sh2lo[g][1][lane * HSTR + kk]) << 16);
        }
        float pacc = b2[0];
        #pragma unroll 1
        for (int jj = 0; jj < 16; ++jj) {
            float acc = b1[jj];
            #pragma unroll
            for (int kk = 0; kk < 32; ++kk) acc += W1[jj * 32 + kk] * h2v[kk];
            pacc += W2[jj] * fmaxf(acc, 0.f);
        }
        out[blockIdx.x * 16 + g * 8 + lane] = pacc;
    }
}

} // namespace

extern "C" void kernel_launch(void* const* d_in, const int* in_sizes, int n_in,
                              void* d_out, int out_size, void* d_ws, size_t ws_size,
                              hipStream_t stream) {
    const float* x    = (const float*)d_in[0];
    const float* Wih0 = (const float*)d_in[1];
    const float* Whh0 = (const float*)d_in[2];
    const float* bih0 = (const float*)d_in[3];
    const float* bhh0 = (const float*)d_in[4];
    const float* Wih1 = (const float*)d_in[5];
    const float* Whh1 = (const float*)d_in[6];
    const float* bih1 = (const float*)d_in[7];
    const float* bhh1 = (const float*)d_in[8];
    const float* W1   = (const float*)d_in[9];
    const float* b1   = (const float*)d_in[10];
    const float* W2   = (const float*)d_in[11];
    const float* b2   = (const float*)d_in[12];

    const int batch  = out_size;            // 4096
    const int blocks = batch / 16;          // 256 blocks x 8 waves (2 groups x 8 rows)

    hipLaunchKernelGGL(lstm2_dual8_kernel, dim3(blocks), dim3(512), 0, stream,
                       x, Wih0, Whh0, bih0, bhh0, Wih1, Whh1, bih1, bhh1,
                       W1, b1, W2, b2, (float*)d_out);
}

// Round 8
// 511.359 us; speedup vs baseline: 2.1992x; 1.4995x over previous
//
#include <hip/hip_runtime.h>

namespace {

typedef __attribute__((ext_vector_type(8))) short short8;   // 8 bf16 (4 VGPRs)
typedef __attribute__((ext_vector_type(4))) float f32x4;

constexpr int T_LEN = 512;
constexpr int HSTR  = 40;    // h-plane row stride (shorts): 32 used + 8 pad

__device__ __forceinline__ float fsig(float x) {
    return __builtin_amdgcn_rcpf(1.0f + __expf(-x));
}
__device__ __forceinline__ float ftanh(float x) {
    return 2.0f * __builtin_amdgcn_rcpf(1.0f + __expf(-2.0f * x)) - 1.0f;
}
__device__ __forceinline__ f32x4 mfma16(short8 a, short8 b, f32x4 c) {
    return __builtin_amdgcn_mfma_f32_16x16x32_bf16(a, b, c, 0, 0, 0);
}
// pack bf16-truncations of (a,b) into one dword, b in LOW short
__device__ __forceinline__ unsigned permhi(float a, float b) {
    return __builtin_amdgcn_perm(__float_as_uint(a), __float_as_uint(b), 0x07060302u);
}
__device__ __forceinline__ float lo_resid(float v) {
    return v - __uint_as_float(__float_as_uint(v) & 0xffff0000u);
}
__device__ __forceinline__ short hi16(float v) {
    return (short)(__float_as_uint(v) >> 16);
}

// Relaxed per-step sync: drain LDS ops (handoff visibility) but let the P-waves'
// global x loads stay in flight across the barrier (no vmcnt(0) drain). All
// cross-wave traffic here is LDS. R5 validated correctness of this barrier.
__device__ __forceinline__ void step_sync() {
    asm volatile("s_waitcnt lgkmcnt(0)" ::: "memory");
    __builtin_amdgcn_s_barrier();
    __builtin_amdgcn_sched_barrier(0);
}

__device__ __forceinline__ void load_x(int q, const float4* xg4, int n, int t,
                                       float4& ra, float4& rb) {
    if (q < 2) {
        const float4* s = xg4 + (size_t)n * (T_LEN * 4) + (size_t)t * 4 + 2 * q;
        ra = s[0]; rb = s[1];
    }
}

__device__ __forceinline__ void pack_x(int q, const float4& va, const float4& vb,
                                       short8& xh8, short8& xl8) {
    if (q < 2) {
        union { short8 s; uint4 u; } h, l;
        h.u.x = permhi(va.y, va.x); h.u.y = permhi(va.w, va.z);
        h.u.z = permhi(vb.y, vb.x); h.u.w = permhi(vb.w, vb.z);
        l.u.x = permhi(lo_resid(va.y), lo_resid(va.x));
        l.u.y = permhi(lo_resid(va.w), lo_resid(va.z));
        l.u.z = permhi(lo_resid(vb.y), lo_resid(vb.x));
        l.u.w = permhi(lo_resid(vb.w), lo_resid(vb.z));
        xh8 = h.s; xl8 = l.s;
    }
}

__device__ __forceinline__ void ew_write(const f32x4 (&gg)[4], float (&cst)[4],
                                         short* dhi, short* dlo, int q, int n, int p) {
    #pragma unroll
    for (int r = 0; r < 4; ++r) {
        const float ig = fsig(gg[0][r]);
        const float fg = fsig(gg[1][r]);
        const float gv = ftanh(gg[2][r]);
        const float og = fsig(gg[3][r]);
        const float cc = fg * cst[r] + ig * gv;
        cst[r] = cc;
        const float hv = og * ftanh(cc);
        const int ro = (q * 4 + r) * HSTR + 2 * n + p;
        dhi[ro] = hi16(hv);
        dlo[ro] = hi16(lo_resid(hv));
    }
}

// block = 384 threads = 6 waves over the SAME 16 batch rows, 256 blocks.
// w0,w1 = L1 consumers (parity p): 12 MFMA h-terms, C-init = pre[t] from LDS ring.
// w2,w3 = L2 (parity p): R4's two independent 3-chains + add. + MLP head (w2).
// w4,w5 = PRE producers (parity p): load x(t+2) global->regs, pack, 12 MFMA
//         (bias + Wih0*x), write 4-slot LDS ring. Off critical path (2 barriers
//         of slack); wave->SIMD round-robin pairs P with L1, leaves L2 alone.
// Ring safety: L1 reads slot i&3, P writes (i+2)&3 (never equal; 2 barriers
// write->read and read->rewrite). x-LDS staging + chunk barrier deleted.
// All f32 arithmetic bit-identical to the R4 kernel (which passed).
__global__ __launch_bounds__(384)
void lstm2_pcpre_kernel(const float* __restrict__ x,
                        const float* __restrict__ Wih0, const float* __restrict__ Whh0,
                        const float* __restrict__ bih0, const float* __restrict__ bhh0,
                        const float* __restrict__ Wih1, const float* __restrict__ Whh1,
                        const float* __restrict__ bih1, const float* __restrict__ bhh1,
                        const float* __restrict__ W1, const float* __restrict__ b1,
                        const float* __restrict__ W2, const float* __restrict__ b2,
                        float* __restrict__ out)
{
    __shared__ __align__(16) short sh1hi[2][16 * HSTR], sh1lo[2][16 * HSTR]; // h1 ring
    __shared__ __align__(16) short sh2hi[2][16 * HSTR], sh2lo[2][16 * HSTR]; // h2 ring
    __shared__ __align__(16) float spre[2][4][4][256];   // [p][slot][gate][lane*4] 32KB

    const int tid  = threadIdx.x;
    const int wid  = tid >> 6;           // 0,1=L1  2,3=L2  4,5=PRE
    const int lane = tid & 63;
    const int q    = lane >> 4;          // quad
    const int n    = lane & 15;          // MFMA col (B: unit col) / A batch row
    const int p    = wid & 1;            // unit parity owned by this wave
    const bool isL1 = (wid < 2);
    const bool isL2 = (wid >= 2 && wid < 4);
    const bool isP  = (wid >= 4);

    // ---- zero h planes ----
    for (int i = tid; i < 16 * HSTR; i += 384) {
        sh1hi[0][i] = 0; sh1hi[1][i] = 0; sh1lo[0][i] = 0; sh1lo[1][i] = 0;
        sh2hi[0][i] = 0; sh2hi[1][i] = 0; sh2lo[0][i] = 0; sh2lo[1][i] = 0;
    }

    // ---- per-wave persistent weight B-fragments + bias C-operands ----
    // L1/P weight map: frag0 = Whh0 (K 0..31), frag1 = [Wih0 (k<16) | 0]
    // L2 weight map:   frag0 = Wih1 (h1 terms), frag1 = Whh1 (h2 terms)
    const bool useL1W = !isL2;
    short8 bh[4][2], bl[4][2];
    f32x4  bsp[4];
    #pragma unroll
    for (int gate = 0; gate < 4; ++gate) {
        const int row = gate * 32 + 2 * n + p;
        #pragma unroll
        for (int f = 0; f < 2; ++f) {
            #pragma unroll
            for (int e = 0; e < 8; ++e) {
                const int kk = f * 32 + q * 8 + e;
                float v;
                if (useL1W) v = (kk < 32) ? Whh0[row * 32 + kk]
                              : (kk < 48) ? Wih0[row * 16 + (kk - 32)] : 0.0f;
                else        v = (kk < 32) ? Wih1[row * 32 + kk]
                                          : Whh1[row * 32 + (kk - 32)];
                const unsigned b = __float_as_uint(v);
                bh[gate][f][e] = (short)(b >> 16);
                const float hif = __uint_as_float(b & 0xffff0000u);
                bl[gate][f][e] = (short)(__float_as_uint(v - hif) >> 16);
            }
        }
        const float bv = useL1W ? (bih0[row] + bhh0[row]) : (bih1[row] + bhh1[row]);
        bsp[gate] = (f32x4){bv, bv, bv, bv};
    }

    float cst[4];                        // c-state (c1 for L1 waves, c2 for L2 waves)
    #pragma unroll
    for (int r = 0; r < 4; ++r) cst[r] = 0.f;

    const float4* xg4 = (const float4*)x + (size_t)blockIdx.x * 16 * (T_LEN * 4);

    // ---- P prologue: build pre(0) -> slot0, pre(1) -> slot1; prefetch x(2) ----
    float4 r0a{}, r0b{};
    short8 xh = (short8)(short)0, xl = (short8)(short)0;
    if (isP) {
        #pragma unroll
        for (int t0 = 0; t0 < 2; ++t0) {
            load_x(q, xg4, n, t0, r0a, r0b);
            pack_x(q, r0a, r0b, xh, xl);
            #pragma unroll
            for (int g2 = 0; g2 < 4; ++g2) {
                f32x4 c = mfma16(xh, bh[g2][1], bsp[g2]);
                c = mfma16(xl, bh[g2][1], c);
                c = mfma16(xh, bl[g2][1], c);
                *(f32x4*)&spre[p][t0][g2][lane * 4] = c;
            }
        }
        load_x(q, xg4, n, 2, r0a, r0b);
    }

    step_sync();                         // zeros + pre(0),pre(1) visible

    #pragma unroll 1
    for (int i = 0; i <= T_LEN; ++i) {
        if (isL1) {
            if (i < T_LEN) {
                const int t = i;
                const int ps = (t + 1) & 1;           // slot holding h1_{t-1}
                const int cs = t & 1;                 // slot receiving h1_t
                const int sl = t & 3;                 // pre ring slot
                const short8 a0h = *(const short8*)&sh1hi[ps][n * HSTR + q * 8];
                const short8 a0l = *(const short8*)&sh1lo[ps][n * HSTR + q * 8];
                f32x4 gg[4];
                #pragma unroll
                for (int g2 = 0; g2 < 4; ++g2) {
                    f32x4 c = *(const f32x4*)&spre[p][sl][g2][lane * 4];
                    c = mfma16(a0h, bh[g2][0], c);
                    c = mfma16(a0l, bh[g2][0], c);
                    c = mfma16(a0h, bl[g2][0], c);
                    gg[g2] = c;
                }
                ew_write(gg, cst, &sh1hi[cs][0], &sh1lo[cs][0], q, n, p);
            }
        } else if (isL2) {
            if (i >= 1) {
                const int t = i - 1;
                const int s1  = t & 1;                // slot holding h1_t
                const int ps2 = (t + 1) & 1;          // slot holding h2_{t-1}
                const short8 a0h = *(const short8*)&sh1hi[s1][n * HSTR + q * 8];
                const short8 a0l = *(const short8*)&sh1lo[s1][n * HSTR + q * 8];
                const short8 a1h = *(const short8*)&sh2hi[ps2][n * HSTR + q * 8];
                const short8 a1l = *(const short8*)&sh2lo[ps2][n * HSTR + q * 8];
                f32x4 gg[4];
                #pragma unroll
                for (int g2 = 0; g2 < 4; ++g2) {
                    f32x4 c1 = mfma16(a0h, bh[g2][0], bsp[g2]);
                    c1 = mfma16(a0l, bh[g2][0], c1);
                    c1 = mfma16(a0h, bl[g2][0], c1);
                    f32x4 c2 = mfma16(a1h, bh[g2][1], (f32x4){0.f, 0.f, 0.f, 0.f});
                    c2 = mfma16(a1l, bh[g2][1], c2);
                    c2 = mfma16(a1h, bl[g2][1], c2);
                    gg[g2] = c1 + c2;
                }
                ew_write(gg, cst, &sh2hi[t & 1][0], &sh2lo[t & 1][0], q, n, p);
            }
        } else { // PRE producer
            if (i + 2 < T_LEN) {
                pack_x(q, r0a, r0b, xh, xl);          // regs hold x(i+2)
                const int sl = (i + 2) & 3;
                #pragma unroll
                for (int g2 = 0; g2 < 4; ++g2) {
                    f32x4 c = mfma16(xh, bh[g2][1], bsp[g2]);
                    c = mfma16(xl, bh[g2][1], c);
                    c = mfma16(xh, bl[g2][1], c);
                    *(f32x4*)&spre[p][sl][g2][lane * 4] = c;
                }
                if (i + 3 < T_LEN) load_x(q, xg4, n, i + 3, r0a, r0b);
            }
        }
        step_sync();
    }

    // ---- MLP head on h2_{T-1} (slot 511&1 = 1) ----
    if (wid == 2 && lane < 16) {
        float h2v[32];
        #pragma unroll
        for (int kk = 0; kk < 32; ++kk) {
            h2v[kk] = __uint_as_float(((unsigned)(unsigned short)sh2hi[1][lane * HSTR + kk]) << 16)
                    + __uint_as_float(((unsigned)(unsigned short)sh2lo[1][lane * HSTR + kk]) << 16);
        }
        float pacc = b2[0];
        #pragma unroll 1
        for (int jj = 0; jj < 16; ++jj) {
            float acc = b1[jj];
            #pragma unroll
            for (int kk = 0; kk < 32; ++kk) acc += W1[jj * 32 + kk] * h2v[kk];
            pacc += W2[jj] * fmaxf(acc, 0.f);
        }
        out[blockIdx.x * 16 + lane] = pacc;
    }
}

} // namespace

extern "C" void kernel_launch(void* const* d_in, const int* in_sizes, int n_in,
                              void* d_out, int out_size, void* d_ws, size_t ws_size,
                              hipStream_t stream) {
    const float* x    = (const float*)d_in[0];
    const float* Wih0 = (const float*)d_in[1];
    const float* Whh0 = (const float*)d_in[2];
    const float* bih0 = (const float*)d_in[3];
    const float* bhh0 = (const float*)d_in[4];
    const float* Wih1 = (const float*)d_in[5];
    const float* Whh1 = (const float*)d_in[6];
    const float* bih1 = (const float*)d_in[7];
    const float* bhh1 = (const float*)d_in[8];
    const float* W1   = (const float*)d_in[9];
    const float* b1   = (const float*)d_in[10];
    const float* W2   = (const float*)d_in[11];
    const float* b2   = (const float*)d_in[12];

    const int batch  = out_size;            // 4096
    const int blocks = batch / 16;          // 256 blocks x 6 waves

    hipLaunchKernelGGL(lstm2_pcpre_kernel, dim3(blocks), dim3(384), 0, stream,
                       x, Wih0, Whh0, bih0, bhh0, Wih1, Whh1, bih1, bhh1,
                       W1, b1, W2, b2, (float*)d_out);
}